// Round 7
// baseline (5266.748 us; speedup 1.0000x reference)
//
#include <hip/hip_runtime.h>
#include <hip/hip_bf16.h>

#define NN   16384
#define IND  512
#define HID  256
#define SAMP 8
#define CAP  64          // max nonzeros per adjacency row (mean ~16.4, P(>64) ~ e^-33)

typedef __bf16 bf16;
typedef __bf16 bf16x4 __attribute__((ext_vector_type(4)));
typedef __bf16 bf16x8 __attribute__((ext_vector_type(8)));
typedef float  f32x4  __attribute__((ext_vector_type(4)));

#define LOG2E_2 2.8853900817779268f   // 2/tau * log2(e) = 2*log2(e)

// async global->LDS, 16B per lane; LDS dest = wave-uniform base + lane*16
#define GLOAD_LDS16(gptr, lptr) \
  __builtin_amdgcn_global_load_lds((const __attribute__((address_space(1))) void*)(gptr), \
                                   (__attribute__((address_space(3))) void*)(lptr), 16, 0, 0)

// ---------------------------------------------------------------- conversions
__global__ void cvt_x(const float* __restrict__ a, bf16* __restrict__ oa,
                      const float* __restrict__ b, bf16* __restrict__ ob) {
  const float* src = blockIdx.y ? b : a;
  bf16* dst = blockIdx.y ? ob : oa;
  int stride = gridDim.x * blockDim.x;
  for (int i = blockIdx.x * blockDim.x + threadIdx.x; i < (NN * IND) / 4; i += stride) {
    float4 v = ((const float4*)src)[i];
    bf16x4 o = {(bf16)v.x, (bf16)v.y, (bf16)v.z, (bf16)v.w};
    *(bf16x4*)(dst + (size_t)i * 4) = o;
  }
}

struct WtArgs {
  const float* src[10];
  bf16* dst[10];
  int K[10];
};

// W [K,256] f32 -> Wt [256,K] bf16 (transposed so GEMM reads K-contiguous rows)
__global__ void cvt_weights(WtArgs a) {
  int w = blockIdx.y;
  int K = a.K[w];
  int total = K * HID;
  const float* s = a.src[w];
  bf16* d = a.dst[w];
  for (int i = blockIdx.x * blockDim.x + threadIdx.x; i < total; i += gridDim.x * blockDim.x) {
    int k = i >> 8, n = i & 255;          // i = k*256 + n
    d[n * K + k] = (bf16)s[i];
  }
}

// ---------------------------------------------------------------- adjacency scan (batched)
__global__ void scan_adj(const float* __restrict__ adjA, const float* __restrict__ adjB,
                         int* __restrict__ colsA, int* __restrict__ cntA,
                         int* __restrict__ colsB, int* __restrict__ cntB) {
  const float* adj = blockIdx.y ? adjB : adjA;
  int* cols = blockIdx.y ? colsB : colsA;
  int* cnt = blockIdx.y ? cntB : cntA;
  int r = blockIdx.x;
  __shared__ int c;
  if (threadIdx.x == 0) c = 0;
  __syncthreads();
  const float4* row = (const float4*)(adj + (size_t)r * NN);
  int* rc = cols + (size_t)r * CAP;
  #pragma unroll 4
  for (int i = threadIdx.x; i < NN / 4; i += 256) {
    float4 v = row[i];
    if (v.x != 0.f || v.y != 0.f || v.z != 0.f || v.w != 0.f) {
      if (v.x != 0.f) { int p = atomicAdd(&c, 1); if (p < CAP) rc[p] = 4 * i; }
      if (v.y != 0.f) { int p = atomicAdd(&c, 1); if (p < CAP) rc[p] = 4 * i + 1; }
      if (v.z != 0.f) { int p = atomicAdd(&c, 1); if (p < CAP) rc[p] = 4 * i + 2; }
      if (v.w != 0.f) { int p = atomicAdd(&c, 1); if (p < CAP) rc[p] = 4 * i + 3; }
    }
  }
  __syncthreads();
  if (threadIdx.x == 0) cnt[r] = (c < CAP) ? c : CAP;
}

// ---------------------------------------------------------------- SpMM (batched, bf16 gather, opt fused l2norm)
struct SpmmB {
  const int* cols[4]; const int* cnt[4]; const bf16* X[4]; const float* bias[4];
  float* outF[4];   // raw f32 (scalar stores; may be 4B-aligned only)
  bf16* outB[4];    // raw bf16
  float* outNF[4];  // l2-normalized f32 (16B-aligned)
};
__global__ void spmm_b(SpmmB s) {
  int j = blockIdx.y;
  int wid = threadIdx.x >> 6, lane = threadIdx.x & 63;
  int r = blockIdx.x * 4 + wid;
  int c = s.cnt[j][r];
  float val = 1.0f / (float)(c > 0 ? c : 1);
  const int* rc = s.cols[j] + (size_t)r * CAP;
  const bf16* X = s.X[j];
  float ax = 0.f, ay = 0.f, az = 0.f, aw = 0.f;
  for (int t = 0; t < c; ++t) {
    int col = rc[t];
    bf16x4 v = *(const bf16x4*)(X + (size_t)col * HID + lane * 4);
    ax += (float)v[0]; ay += (float)v[1]; az += (float)v[2]; aw += (float)v[3];
  }
  float4 b4 = ((const float4*)s.bias[j])[lane];
  ax = ax * val + b4.x; ay = ay * val + b4.y; az = az * val + b4.z; aw = aw * val + b4.w;
  if (s.outF[j]) {
    float* o = s.outF[j] + (size_t)r * HID + lane * 4;
    o[0] = ax; o[1] = ay; o[2] = az; o[3] = aw;
  }
  if (s.outB[j]) {
    bf16x4 ob = {(bf16)ax, (bf16)ay, (bf16)az, (bf16)aw};
    *(bf16x4*)(s.outB[j] + (size_t)r * HID + lane * 4) = ob;
  }
  if (s.outNF[j]) {
    float ss = ax * ax + ay * ay + az * az + aw * aw;
    #pragma unroll
    for (int off = 1; off < 64; off <<= 1) ss += __shfl_xor(ss, off);
    float inv = 1.0f / fmaxf(sqrtf(ss), 1e-12f);
    float4 o = {ax * inv, ay * inv, az * inv, aw * inv};
    ((float4*)(s.outNF[j] + (size_t)r * HID))[lane] = o;
  }
}

// ---------------------------------------------------------------- bf16 GEMM (batched, async staging)
struct GemmB {
  const bf16* A[3]; const bf16* Bt[3]; const float* bias[3];
  float* Cf[3]; bf16* Cb[3];
};
__global__ __launch_bounds__(256) void gemm_b(GemmB g, int K, int relu) {
  __shared__ bf16 As[128][64];
  __shared__ bf16 Bs[128][64];
  int j = blockIdx.z;
  const bf16* A = g.A[j];
  const bf16* Bt = g.Bt[j];
  int m0 = blockIdx.x * 128, n0 = blockIdx.y * 128;
  int tid = threadIdx.x, wid = tid >> 6, lane = tid & 63;
  int wm = wid >> 1, wn = wid & 1, q = lane >> 4, li = lane & 15;
  int r8 = lane >> 3, cc8 = lane & 7;    // 8 rows x 8 chunks per wave-instruction
  int csw = cc8 ^ r8;                    // swizzled source chunk for this lane
  f32x4 acc[4][4] = {};
  for (int k0 = 0; k0 < K; k0 += 64) {
    if (k0) __syncthreads();
    const bf16* gA = A + (size_t)(m0 + wid * 32 + r8) * K + k0 + csw * 8;
    const bf16* gB = Bt + (size_t)(n0 + wid * 32 + r8) * K + k0 + csw * 8;
    #pragma unroll
    for (int jj = 0; jj < 4; ++jj) {
      GLOAD_LDS16(gA + (size_t)jj * 8 * K, &As[wid * 32 + jj * 8][0]);
      GLOAD_LDS16(gB + (size_t)jj * 8 * K, &Bs[wid * 32 + jj * 8][0]);
    }
    __syncthreads();
    #pragma unroll
    for (int kk = 0; kk < 64; kk += 32) {
      int ca = (((q + (kk >> 3)) ^ (li & 7)) << 3);   // un-swizzle (row&7 == li&7)
      bf16x8 af[4], bfr[4];
      #pragma unroll
      for (int im = 0; im < 4; ++im) af[im] = *(const bf16x8*)(&As[wm * 64 + im * 16 + li][ca]);
      #pragma unroll
      for (int in = 0; in < 4; ++in) bfr[in] = *(const bf16x8*)(&Bs[wn * 64 + in * 16 + li][ca]);
      #pragma unroll
      for (int im = 0; im < 4; ++im)
        #pragma unroll
        for (int in = 0; in < 4; ++in)
          acc[im][in] = __builtin_amdgcn_mfma_f32_16x16x32_bf16(af[im], bfr[in], acc[im][in], 0, 0, 0);
    }
  }
  float* Cf = g.Cf[j];
  bf16* Cb = g.Cb[j];
  const float* bias = g.bias[j];
  #pragma unroll
  for (int im = 0; im < 4; ++im) {
    int grow0 = m0 + wm * 64 + im * 16 + q * 4;
    #pragma unroll
    for (int in = 0; in < 4; ++in) {
      int gcol = n0 + wn * 64 + in * 16 + li;
      float bv = bias ? bias[gcol] : 0.f;
      #pragma unroll
      for (int reg = 0; reg < 4; ++reg) {
        float v = acc[im][in][reg] + bv;
        if (relu) v = fmaxf(v, 0.f);
        size_t idx = (size_t)(grow0 + reg) * HID + gcol;
        if (Cf) Cf[idx] = v;
        if (Cb) Cb[idx] = (bf16)v;
      }
    }
  }
}

// ---------------------------------------------------------------- flash semi-loss v6
// Y-stationary in registers (wave owns 64 cols), DUAL streams (same-matrix with
// triangle symmetry + cross-matrix full) share the staged LDS chunks.
//   z=0: Y=P. same: exp(2 P.P^T) -> Ra (upper tri, col+row dual-add).
//              cross: colsum_j exp(2 Q.P^T) = rowsum of exp(2 P.Q^T) -> Cr.
//   z=1: Y=Q. same -> Rb ; cross: colsum exp(2 P.Q^T) -> Cc.
// Block: 512 thr (8 waves = 2/SIMD), LDS 2 x (32KB Xs + 32KB Zs) dbuf,
// one barrier per 64-row chunk. Colsums in registers; rowsums via 4 shfl+atomic.
__global__ __launch_bounds__(512, 2) void flash_sem6(
    const bf16* __restrict__ P, const bf16* __restrict__ Q,
    float* __restrict__ Ra, float* __restrict__ Rb,
    float* __restrict__ Cr, float* __restrict__ Cc) {
  __shared__ bf16 Xs[2][64 * 256];   // same-matrix rows (32 KiB each buf)
  __shared__ bf16 Zs[2][64 * 256];   // cross-matrix rows
  int z = blockIdx.z;
  const bf16* Y  = z ? Q : P;        // stationary columns
  const bf16* Xg = z ? Q : P;        // same-matrix stream
  const bf16* Zg = z ? P : Q;        // cross-matrix stream
  float* outS = z ? Rb : Ra;
  float* outC = z ? Cc : Cr;
  int tid = threadIdx.x, wid = tid >> 6, lane = tid & 63;
  int q = lane >> 4, li = lane & 15;
  int cbase = blockIdx.x * 512;
  int cw = cbase + wid * 64;          // this wave's global col base
  int i0 = blockIdx.y * 4096;         // row-split base
  // stationary Y fragments: 4 col-tiles x 8 k-steps (128 VGPR)
  bf16x8 bfrag[4][8];
  #pragma unroll
  for (int in = 0; in < 4; ++in) {
    const bf16* Yr = Y + (size_t)(cw + in * 16 + li) * HID + q * 8;
    #pragma unroll
    for (int kk = 0; kk < 8; ++kk)
      bfrag[in][kk] = *(const bf16x8*)(Yr + kk * 32);
  }
  float csS[4] = {}, csC[4] = {};
  int l5 = lane >> 5, c16 = lane & 31;
  auto stage = [&](const bf16* g, bf16* ldsbase, int c) {
    const bf16* src = g + (size_t)(i0 + c * 64) * HID;
    #pragma unroll
    for (int n = 0; n < 4; ++n) {
      int rl = wid * 8 + n * 2;               // wave-uniform LDS row pair
      int r = rl + l5;
      int cs_ = c16 ^ (r & 31);               // swizzled source 16B-chunk
      GLOAD_LDS16(src + (size_t)r * HID + cs_ * 8, ldsbase + rl * 256);
    }
  };
  auto needX = [&](int c) { return (i0 + c * 64) < cbase + 512; };
  stage(Zg, &Xs[0][0] + 0, 0);  // placeholder to keep symmetry; real below
  // NOTE: above line intentionally replaced by proper staging:
  // (we re-stage buffer 0 fully here)
  __syncthreads();   // harmless ordering point before real staging
  stage(Zg, &Zs[0][0], 0);
  if (needX(0)) stage(Xg, &Xs[0][0], 0);
  __syncthreads();
  for (int c = 0; c < 64; ++c) {
    int b = c & 1;
    if (c + 1 < 64) {
      stage(Zg, &Zs[b ^ 1][0], c + 1);
      if (needX(c + 1)) stage(Xg, &Xs[b ^ 1][0], c + 1);
    }
    // ---- cross section: full colsum
    #pragma unroll
    for (int ii = 0; ii < 4; ++ii) {
      bf16x8 af[8];
      #pragma unroll
      for (int kk = 0; kk < 8; ++kk) {
        int row = ii * 16 + li;
        af[kk] = *(const bf16x8*)(&Zs[b][row * 256 + (((kk * 4 + q) ^ (row & 31)) << 3)]);
      }
      #pragma unroll
      for (int in = 0; in < 4; ++in) {
        f32x4 acc = {};
        #pragma unroll
        for (int kk = 0; kk < 8; ++kk)
          acc = __builtin_amdgcn_mfma_f32_16x16x32_bf16(af[kk], bfrag[in][kk], acc, 0, 0, 0);
        #pragma unroll
        for (int reg = 0; reg < 4; ++reg)
          csC[in] += exp2f(acc[reg] * LOG2E_2);
      }
    }
    // ---- same section: upper-triangle with dual col/row accumulation
    int rchunk = i0 + c * 64;
    if (rchunk < cbase + 512) {
      #pragma unroll
      for (int ii = 0; ii < 4; ++ii) {
        int rt = rchunk + ii * 16;            // tile row base (global)
        if (rt >= cw + 64) continue;          // all col-tiles below diagonal
        bf16x8 af[8];
        #pragma unroll
        for (int kk = 0; kk < 8; ++kk) {
          int row = ii * 16 + li;
          af[kk] = *(const bf16x8*)(&Xs[b][row * 256 + (((kk * 4 + q) ^ (row & 31)) << 3)]);
        }
        #pragma unroll
        for (int in = 0; in < 4; ++in) {
          int ct = cw + in * 16;
          if (rt >= ct + 16) continue;        // strictly below: mirror handled elsewhere
          f32x4 acc = {};
          #pragma unroll
          for (int kk = 0; kk < 8; ++kk)
            acc = __builtin_amdgcn_mfma_f32_16x16x32_bf16(af[kk], bfrag[in][kk], acc, 0, 0, 0);
          if (rt + 16 <= ct) {
            // strictly above diagonal: add to colsum and (mirrored) rowsum
            #pragma unroll
            for (int reg = 0; reg < 4; ++reg) {
              float e = exp2f(acc[reg] * LOG2E_2);
              csS[in] += e;
              float rs = e;
              rs += __shfl_xor(rs, 1); rs += __shfl_xor(rs, 2);
              rs += __shfl_xor(rs, 4); rs += __shfl_xor(rs, 8);
              if (li == 0) atomicAdd(&outS[rt + q * 4 + reg], rs);
            }
          } else {
            // diagonal tile (rt == ct): per-element masks
            #pragma unroll
            for (int reg = 0; reg < 4; ++reg) {
              float e = exp2f(acc[reg] * LOG2E_2);
              int row = q * 4 + reg;
              csS[in] += (row <= li) ? e : 0.f;
              float rs = (row < li) ? e : 0.f;
              rs += __shfl_xor(rs, 1); rs += __shfl_xor(rs, 2);
              rs += __shfl_xor(rs, 4); rs += __shfl_xor(rs, 8);
              if (li == 0) atomicAdd(&outS[rt + row], rs);
            }
          }
        }
      }
    }
    __syncthreads();   // drains prefetch vmcnt + protects dbuf swap
  }
  #pragma unroll
  for (int in = 0; in < 4; ++in) {
    float v = csC[in];
    v += __shfl_xor(v, 16); v += __shfl_xor(v, 32);
    if (q == 0) atomicAdd(&outC[cw + in * 16 + li], v);
    float u = csS[in];
    u += __shfl_xor(u, 16); u += __shfl_xor(u, 32);
    if (q == 0) atomicAdd(&outS[cw + in * 16 + li], u);
  }
}

// ---------------------------------------------------------------- l2norm (batched, one wave/row)
struct NormB { const float* X[3]; float* outF[3]; bf16* outB[3]; };
__global__ void l2norm_b(NormB n) {
  int j = blockIdx.y;
  int wid = threadIdx.x >> 6, lane = threadIdx.x & 63;
  int r = blockIdx.x * 4 + wid;
  float4 a = ((const float4*)(n.X[j] + (size_t)r * HID))[lane];
  float s = a.x * a.x + a.y * a.y + a.z * a.z + a.w * a.w;
  #pragma unroll
  for (int off = 1; off < 64; off <<= 1) s += __shfl_xor(s, off);
  float inv = 1.0f / fmaxf(sqrtf(s), 1e-12f);
  a.x *= inv; a.y *= inv; a.z *= inv; a.w *= inv;
  if (n.outF[j]) ((float4*)(n.outF[j] + (size_t)r * HID))[lane] = a;
  if (n.outB[j]) {
    bf16x4 b = {(bf16)a.x, (bf16)a.y, (bf16)a.z, (bf16)a.w};
    *(bf16x4*)(n.outB[j] + (size_t)r * HID + lane * 4) = b;
  }
}

// ---------------------------------------------------------------- tail: contrastive (y=0) + sem finalize (y=1)
__global__ void tail_k(const float* __restrict__ proj, const float* __restrict__ vn,
                       const float* __restrict__ ue, const int* __restrict__ nbr,
                       const int* __restrict__ neg,
                       const float* __restrict__ P, const float* __restrict__ Q2,
                       const float* __restrict__ Ra, const float* __restrict__ Rb,
                       const float* __restrict__ Cr, const float* __restrict__ Cc,
                       float* __restrict__ sums) {
  int wid = threadIdx.x >> 6, lane = threadIdx.x & 63;
  int n = blockIdx.x * 4 + wid;
  if (blockIdx.y == 0) {
    float4 p = ((const float4*)(proj + (size_t)n * HID))[lane];
    float4 v = ((const float4*)(vn + (size_t)n * HID))[lane];
    float du[SAMP], dn[SAMP];
    for (int s = 0; s < SAMP; ++s) {
      int iu = nbr[n * SAMP + s];
      float4 u = ((const float4*)(ue + (size_t)iu * HID))[lane];
      float d = p.x * u.x + p.y * u.y + p.z * u.z + p.w * u.w;
      #pragma unroll
      for (int off = 1; off < 64; off <<= 1) d += __shfl_xor(d, off);
      du[s] = d;
      int iv = neg[n * SAMP + s];
      float4 w = ((const float4*)(vn + (size_t)iv * HID))[lane];
      float d2 = v.x * w.x + v.y * w.y + v.z * w.z + v.w * w.w;
      #pragma unroll
      for (int off = 1; off < 64; off <<= 1) d2 += __shfl_xor(d2, off);
      dn[s] = d2;
    }
    float negsum = 0.f;
    for (int s = 0; s < SAMP; ++s) negsum += expf(2.f * dn[s]);
    float ns = 0.f, ps = 0.f;
    for (int s = 0; s < SAMP; ++s) {
      float pl = 2.f * du[s];
      ns += logf(expf(pl) + negsum);
      ps += pl;
    }
    if (lane == 0) atomicAdd(&sums[0], ns - ps);   // LAMBDA = 1
  } else {
    float4 a = ((const float4*)(P + (size_t)n * HID))[lane];
    float4 b = ((const float4*)(Q2 + (size_t)n * HID))[lane];
    float d = a.x * b.x + a.y * b.y + a.z * b.z + a.w * b.w;
    #pragma unroll
    for (int off = 1; off < 64; off <<= 1) d += __shfl_xor(d, off);
    float db = expf(2.f * d);
    float e2 = expf(2.f);      // diag(refl) of unit-norm rows
    float l1 = -logf(db / (Ra[n] + Cr[n] - e2));
    float l2 = -logf(db / (Rb[n] + Cc[n] - e2));
    if (lane == 0) atomicAdd(&sums[1], 0.5f * (l1 + l2));
  }
}

__global__ void final_k(const float* __restrict__ sums, float* __restrict__ out) {
  float gacl = sums[0] / (float)(NN * SAMP);
  float sem = sums[1] / (float)NN;
  out[0] = gacl + 0.6f * sem;
  out[1] = gacl;
  out[2] = sem;
}

// ---------------------------------------------------------------- launch
extern "C" void kernel_launch(void* const* d_in, const int* in_sizes, int n_in,
                              void* d_out, int out_size, void* d_ws, size_t ws_size,
                              hipStream_t stream) {
  (void)in_sizes; (void)n_in; (void)out_size; (void)ws_size;
  const float* adj1 = (const float*)d_in[0];
  const float* adj2 = (const float*)d_in[1];
  const float* x1 = (const float*)d_in[2];
  const float* x2 = (const float*)d_in[3];
  const int* nbr = (const int*)d_in[4];
  const int* neg = (const int*)d_in[5];
  const float* W1 = (const float*)d_in[6];
  const float* b1 = (const float*)d_in[7];
  const float* W2 = (const float*)d_in[8];
  const float* b2 = (const float*)d_in[9];
  const float* tW1 = (const float*)d_in[10];
  const float* tb1 = (const float*)d_in[11];
  const float* tW2 = (const float*)d_in[12];
  const float* tb2 = (const float*)d_in[13];
  const float* pB[3] = {(const float*)d_in[15], (const float*)d_in[17], (const float*)d_in[19]};
  const float* sB[3] = {(const float*)d_in[21], (const float*)d_in[23], (const float*)d_in[25]};

  char* w = (char*)d_ws;
  auto alloc = [&](size_t bytes) -> char* {
    char* p = w;
    w += (bytes + 255) & ~(size_t)255;
    return p;
  };
  // accumulators first (one memset covers them)
  float* Ra = (float*)alloc((size_t)NN * 4);
  float* Rb = (float*)alloc((size_t)NN * 4);
  float* Cr = (float*)alloc((size_t)NN * 4);
  float* Cc = (float*)alloc((size_t)NN * 4);
  float* sums = (float*)alloc(256);             // [0]=gacl_sum, [1]=sem_sum
  size_t accBytes = (size_t)(w - (char*)d_ws);

  int* c1cols = (int*)alloc((size_t)NN * CAP * 4);
  int* c1cnt = (int*)alloc((size_t)NN * 4);
  int* c2cols = (int*)alloc((size_t)NN * CAP * 4);
  int* c2cnt = (int*)alloc((size_t)NN * 4);
  bf16* x1b = (bf16*)alloc((size_t)NN * IND * 2);
  bf16* x2b = (bf16*)alloc((size_t)NN * IND * 2);
  bf16* W1t = (bf16*)alloc((size_t)IND * HID * 2);
  bf16* tW1t = (bf16*)alloc((size_t)IND * HID * 2);
  bf16* W2t = (bf16*)alloc((size_t)HID * HID * 2);
  bf16* tW2t = (bf16*)alloc((size_t)HID * HID * 2);
  bf16* pWt[3], *sWt[3];
  for (int i = 0; i < 3; ++i) pWt[i] = (bf16*)alloc((size_t)HID * HID * 2);
  for (int i = 0; i < 3; ++i) sWt[i] = (bf16*)alloc((size_t)HID * HID * 2);
  const size_t BB = (size_t)NN * HID * 2;       // 8 MiB bf16 buffers
  bf16* xw1b = (bf16*)alloc(BB);
  bf16* xw2b = (bf16*)alloc(BB);
  bf16* xt1b = (bf16*)alloc(BB);
  bf16* gwb = (bf16*)alloc(BB);
  bf16* utwb = (bf16*)alloc(BB);
  bf16* h1b = (bf16*)alloc(BB);
  bf16* h2b = (bf16*)alloc(BB);
  bf16* gb_ = (bf16*)alloc(BB);
  bf16* h3b = (bf16*)alloc(BB);
  bf16* utb = (bf16*)alloc(BB);
  bf16* mA = (bf16*)alloc(BB);
  bf16* mB = (bf16*)alloc(BB);
  bf16* mB1 = (bf16*)alloc(BB);
  bf16* mB2 = (bf16*)alloc(BB);
  bf16* Pb = (bf16*)alloc(BB);
  bf16* Qb = (bf16*)alloc(BB);
  const size_t FB = (size_t)NN * HID * 4;       // 16 MiB f32 buffers
  float* u_emd = (float*)alloc(FB);
  float* v_norm = (float*)alloc(FB);
  float* projected = (float*)alloc(FB);
  float* h1p = (float*)alloc(FB);
  float* h2p = (float*)alloc(FB);
  float* mlp_out = (float*)alloc(FB);
  float* s3a = (float*)alloc(FB);
  float* s3b = (float*)alloc(FB);

  hipMemsetAsync(d_ws, 0, accBytes, stream);

  WtArgs wa;
  const float* wsrc[10] = {W1, tW1, W2, tW2,
                           (const float*)d_in[14], (const float*)d_in[16], (const float*)d_in[18],
                           (const float*)d_in[20], (const float*)d_in[22], (const float*)d_in[24]};
  bf16* wdst[10] = {W1t, tW1t, W2t, tW2t, pWt[0], pWt[1], pWt[2], sWt[0], sWt[1], sWt[2]};
  int wk[10] = {IND, IND, HID, HID, HID, HID, HID, HID, HID, HID};
  for (int i = 0; i < 10; ++i) { wa.src[i] = wsrc[i]; wa.dst[i] = wdst[i]; wa.K[i] = wk[i]; }
  cvt_weights<<<dim3(512, 10), 256, 0, stream>>>(wa);
  cvt_x<<<dim3(2048, 2), 256, 0, stream>>>(x1, x1b, x2, x2b);
  scan_adj<<<dim3(NN, 2), 256, 0, stream>>>(adj1, adj2, c1cols, c1cnt, c2cols, c2cnt);

  // xw1 = x1@W1, xw2 = x2@W1, xt1 = x1@tW1  (K=512, batched, bf16 out)
  {
    GemmB g = {};
    g.A[0] = x1b; g.Bt[0] = W1t; g.Cb[0] = xw1b;
    g.A[1] = x2b; g.Bt[1] = W1t; g.Cb[1] = xw2b;
    g.A[2] = x1b; g.Bt[2] = tW1t; g.Cb[2] = xt1b;
    gemm_b<<<dim3(128, 2, 3), 256, 0, stream>>>(g, IND, 0);
  }
  // h1 = A1@xw1+b1, h2 = A1@xw2+b1, g = A2@xw1+b1, ut = A2@xt1+tb1
  {
    SpmmB s = {};
    s.cols[0] = c1cols; s.cnt[0] = c1cnt; s.X[0] = xw1b; s.bias[0] = b1; s.outB[0] = h1b;
    s.cols[1] = c1cols; s.cnt[1] = c1cnt; s.X[1] = xw2b; s.bias[1] = b1; s.outB[1] = h2b;
    s.cols[2] = c2cols; s.cnt[2] = c2cnt; s.X[2] = xw1b; s.bias[2] = b1; s.outB[2] = gb_;
    s.cols[3] = c2cols; s.cnt[3] = c2cnt; s.X[3] = xt1b; s.bias[3] = tb1; s.outB[3] = utb;
    spmm_b<<<dim3(NN / 4, 4), 256, 0, stream>>>(s);
  }
  // gw = g@W2, utw = ut@tW2 (K=256, batched, bf16 out)
  {
    GemmB g = {};
    g.A[0] = gb_; g.Bt[0] = W2t; g.Cb[0] = gwb;
    g.A[1] = utb; g.Bt[1] = tW2t; g.Cb[1] = utwb;
    gemm_b<<<dim3(128, 2, 2), 256, 0, stream>>>(g, HID, 0);
  }
  // h3 = A2@gw+b2 (-> d_out+3, h3b, v_norm) ; u_emd = l2norm(A2@utw+tb2)
  float* h3out = ((float*)d_out) + 3;
  {
    SpmmB s = {};
    s.cols[0] = c2cols; s.cnt[0] = c2cnt; s.X[0] = gwb; s.bias[0] = b2;
    s.outF[0] = h3out; s.outB[0] = h3b; s.outNF[0] = v_norm;
    s.cols[1] = c2cols; s.cnt[1] = c2cnt; s.X[1] = utwb; s.bias[1] = tb2;
    s.outNF[1] = u_emd;
    spmm_b<<<dim3(NN / 4, 2), 256, 0, stream>>>(s);
  }
  // MLP layer 1 (relu): proj(h3b), sem(h1b), sem(h2b)
  {
    GemmB g = {};
    g.A[0] = h3b; g.Bt[0] = pWt[0]; g.bias[0] = pB[0]; g.Cb[0] = mA;
    g.A[1] = h1b; g.Bt[1] = sWt[0]; g.bias[1] = sB[0]; g.Cb[1] = gb_;
    g.A[2] = h2b; g.Bt[2] = sWt[0]; g.bias[2] = sB[0]; g.Cb[2] = utb;
    gemm_b<<<dim3(128, 2, 3), 256, 0, stream>>>(g, HID, 1);
  }
  // MLP layer 2 (relu)
  {
    GemmB g = {};
    g.A[0] = mA; g.Bt[0] = pWt[1]; g.bias[0] = pB[1]; g.Cb[0] = mB;
    g.A[1] = gb_; g.Bt[1] = sWt[1]; g.bias[1] = sB[1]; g.Cb[1] = mB1;
    g.A[2] = utb; g.Bt[2] = sWt[1]; g.bias[2] = sB[1]; g.Cb[2] = mB2;
    gemm_b<<<dim3(128, 2, 3), 256, 0, stream>>>(g, HID, 1);
  }
  // MLP layer 3 (no relu) -> f32
  {
    GemmB g = {};
    g.A[0] = mB; g.Bt[0] = pWt[2]; g.bias[0] = pB[2]; g.Cf[0] = mlp_out;
    g.A[1] = mB1; g.Bt[1] = sWt[2]; g.bias[1] = sB[2]; g.Cf[1] = s3a;
    g.A[2] = mB2; g.Bt[2] = sWt[2]; g.bias[2] = sB[2]; g.Cf[2] = s3b;
    gemm_b<<<dim3(128, 2, 3), 256, 0, stream>>>(g, HID, 0);
  }
  // l2norm: projected, h1p(+Pb), h2p(+Qb)
  {
    NormB nb2 = {};
    nb2.X[0] = mlp_out; nb2.outF[0] = projected;
    nb2.X[1] = s3a; nb2.outF[1] = h1p; nb2.outB[1] = Pb;
    nb2.X[2] = s3b; nb2.outF[2] = h2p; nb2.outB[2] = Qb;
    l2norm_b<<<dim3(NN / 4, 3), 256, 0, stream>>>(nb2);
  }

  flash_sem6<<<dim3(32, 4, 2), 512, 0, stream>>>(Pb, Qb, Ra, Rb, Cr, Cc);
  tail_k<<<dim3(NN / 4, 2), 256, 0, stream>>>(projected, v_norm, u_emd, nbr, neg,
                                              h1p, h2p, Ra, Rb, Cr, Cc, sums);
  final_k<<<1, 1, 0, stream>>>(sums, (float*)d_out);
}

// Round 8
// 3443.114 us; speedup vs baseline: 1.5296x; 1.5296x over previous
//
#include <hip/hip_runtime.h>
#include <hip/hip_bf16.h>

#define NN   16384
#define IND  512
#define HID  256
#define SAMP 8
#define CAP  64          // max nonzeros per adjacency row (mean ~16.4, P(>64) ~ e^-33)

typedef __bf16 bf16;
typedef __bf16 bf16x4 __attribute__((ext_vector_type(4)));
typedef __bf16 bf16x8 __attribute__((ext_vector_type(8)));
typedef float  f32x4  __attribute__((ext_vector_type(4)));

#define LOG2E_2 2.8853900817779268f   // 2/tau * log2(e) = 2*log2(e)

// async global->LDS, 16B per lane; LDS dest = wave-uniform base + lane*16
#define GLOAD_LDS16(gptr, lptr) \
  __builtin_amdgcn_global_load_lds((const __attribute__((address_space(1))) void*)(gptr), \
                                   (__attribute__((address_space(3))) void*)(lptr), 16, 0, 0)

// ---------------------------------------------------------------- conversions
__global__ void cvt_x(const float* __restrict__ a, bf16* __restrict__ oa,
                      const float* __restrict__ b, bf16* __restrict__ ob) {
  const float* src = blockIdx.y ? b : a;
  bf16* dst = blockIdx.y ? ob : oa;
  int stride = gridDim.x * blockDim.x;
  for (int i = blockIdx.x * blockDim.x + threadIdx.x; i < (NN * IND) / 4; i += stride) {
    float4 v = ((const float4*)src)[i];
    bf16x4 o = {(bf16)v.x, (bf16)v.y, (bf16)v.z, (bf16)v.w};
    *(bf16x4*)(dst + (size_t)i * 4) = o;
  }
}

struct WtArgs {
  const float* src[10];
  bf16* dst[10];
  int K[10];
};

// W [K,256] f32 -> Wt [256,K] bf16 (transposed so GEMM reads K-contiguous rows)
__global__ void cvt_weights(WtArgs a) {
  int w = blockIdx.y;
  int K = a.K[w];
  int total = K * HID;
  const float* s = a.src[w];
  bf16* d = a.dst[w];
  for (int i = blockIdx.x * blockDim.x + threadIdx.x; i < total; i += gridDim.x * blockDim.x) {
    int k = i >> 8, n = i & 255;          // i = k*256 + n
    d[n * K + k] = (bf16)s[i];
  }
}

// ---------------------------------------------------------------- adjacency scan (batched)
__global__ void scan_adj(const float* __restrict__ adjA, const float* __restrict__ adjB,
                         int* __restrict__ colsA, int* __restrict__ cntA,
                         int* __restrict__ colsB, int* __restrict__ cntB) {
  const float* adj = blockIdx.y ? adjB : adjA;
  int* cols = blockIdx.y ? colsB : colsA;
  int* cnt = blockIdx.y ? cntB : cntA;
  int r = blockIdx.x;
  __shared__ int c;
  if (threadIdx.x == 0) c = 0;
  __syncthreads();
  const float4* row = (const float4*)(adj + (size_t)r * NN);
  int* rc = cols + (size_t)r * CAP;
  #pragma unroll 4
  for (int i = threadIdx.x; i < NN / 4; i += 256) {
    float4 v = row[i];
    if (v.x != 0.f || v.y != 0.f || v.z != 0.f || v.w != 0.f) {
      if (v.x != 0.f) { int p = atomicAdd(&c, 1); if (p < CAP) rc[p] = 4 * i; }
      if (v.y != 0.f) { int p = atomicAdd(&c, 1); if (p < CAP) rc[p] = 4 * i + 1; }
      if (v.z != 0.f) { int p = atomicAdd(&c, 1); if (p < CAP) rc[p] = 4 * i + 2; }
      if (v.w != 0.f) { int p = atomicAdd(&c, 1); if (p < CAP) rc[p] = 4 * i + 3; }
    }
  }
  __syncthreads();
  if (threadIdx.x == 0) cnt[r] = (c < CAP) ? c : CAP;
}

// ---------------------------------------------------------------- SpMM (batched, bf16 gather, opt fused l2norm)
struct SpmmB {
  const int* cols[4]; const int* cnt[4]; const bf16* X[4]; const float* bias[4];
  float* outF[4];   // raw f32 (scalar stores; may be 4B-aligned only)
  bf16* outB[4];    // raw bf16
  float* outNF[4];  // l2-normalized f32 (16B-aligned)
};
__global__ void spmm_b(SpmmB s) {
  int j = blockIdx.y;
  int wid = threadIdx.x >> 6, lane = threadIdx.x & 63;
  int r = blockIdx.x * 4 + wid;
  int c = s.cnt[j][r];
  float val = 1.0f / (float)(c > 0 ? c : 1);
  const int* rc = s.cols[j] + (size_t)r * CAP;
  const bf16* X = s.X[j];
  float ax = 0.f, ay = 0.f, az = 0.f, aw = 0.f;
  for (int t = 0; t < c; ++t) {
    int col = rc[t];
    bf16x4 v = *(const bf16x4*)(X + (size_t)col * HID + lane * 4);
    ax += (float)v[0]; ay += (float)v[1]; az += (float)v[2]; aw += (float)v[3];
  }
  float4 b4 = ((const float4*)s.bias[j])[lane];
  ax = ax * val + b4.x; ay = ay * val + b4.y; az = az * val + b4.z; aw = aw * val + b4.w;
  if (s.outF[j]) {
    float* o = s.outF[j] + (size_t)r * HID + lane * 4;
    o[0] = ax; o[1] = ay; o[2] = az; o[3] = aw;
  }
  if (s.outB[j]) {
    bf16x4 ob = {(bf16)ax, (bf16)ay, (bf16)az, (bf16)aw};
    *(bf16x4*)(s.outB[j] + (size_t)r * HID + lane * 4) = ob;
  }
  if (s.outNF[j]) {
    float ss = ax * ax + ay * ay + az * az + aw * aw;
    #pragma unroll
    for (int off = 1; off < 64; off <<= 1) ss += __shfl_xor(ss, off);
    float inv = 1.0f / fmaxf(sqrtf(ss), 1e-12f);
    float4 o = {ax * inv, ay * inv, az * inv, aw * inv};
    ((float4*)(s.outNF[j] + (size_t)r * HID))[lane] = o;
  }
}

// ---------------------------------------------------------------- bf16 GEMM (batched, async staging)
struct GemmB {
  const bf16* A[3]; const bf16* Bt[3]; const float* bias[3];
  float* Cf[3]; bf16* Cb[3];
};
__global__ __launch_bounds__(256) void gemm_b(GemmB g, int K, int relu) {
  __shared__ bf16 As[128][64];
  __shared__ bf16 Bs[128][64];
  int j = blockIdx.z;
  const bf16* A = g.A[j];
  const bf16* Bt = g.Bt[j];
  int m0 = blockIdx.x * 128, n0 = blockIdx.y * 128;
  int tid = threadIdx.x, wid = tid >> 6, lane = tid & 63;
  int wm = wid >> 1, wn = wid & 1, q = lane >> 4, li = lane & 15;
  int r8 = lane >> 3, cc8 = lane & 7;    // 8 rows x 8 chunks per wave-instruction
  int csw = cc8 ^ r8;                    // swizzled source chunk for this lane
  f32x4 acc[4][4] = {};
  for (int k0 = 0; k0 < K; k0 += 64) {
    if (k0) __syncthreads();
    const bf16* gA = A + (size_t)(m0 + wid * 32 + r8) * K + k0 + csw * 8;
    const bf16* gB = Bt + (size_t)(n0 + wid * 32 + r8) * K + k0 + csw * 8;
    #pragma unroll
    for (int jj = 0; jj < 4; ++jj) {
      GLOAD_LDS16(gA + (size_t)jj * 8 * K, &As[wid * 32 + jj * 8][0]);
      GLOAD_LDS16(gB + (size_t)jj * 8 * K, &Bs[wid * 32 + jj * 8][0]);
    }
    __syncthreads();
    #pragma unroll
    for (int kk = 0; kk < 64; kk += 32) {
      int ca = (((q + (kk >> 3)) ^ (li & 7)) << 3);   // un-swizzle (row&7 == li&7)
      bf16x8 af[4], bfr[4];
      #pragma unroll
      for (int im = 0; im < 4; ++im) af[im] = *(const bf16x8*)(&As[wm * 64 + im * 16 + li][ca]);
      #pragma unroll
      for (int in = 0; in < 4; ++in) bfr[in] = *(const bf16x8*)(&Bs[wn * 64 + in * 16 + li][ca]);
      #pragma unroll
      for (int im = 0; im < 4; ++im)
        #pragma unroll
        for (int in = 0; in < 4; ++in)
          acc[im][in] = __builtin_amdgcn_mfma_f32_16x16x32_bf16(af[im], bfr[in], acc[im][in], 0, 0, 0);
    }
  }
  float* Cf = g.Cf[j];
  bf16* Cb = g.Cb[j];
  const float* bias = g.bias[j];
  #pragma unroll
  for (int im = 0; im < 4; ++im) {
    int grow0 = m0 + wm * 64 + im * 16 + q * 4;
    #pragma unroll
    for (int in = 0; in < 4; ++in) {
      int gcol = n0 + wn * 64 + in * 16 + li;
      float bv = bias ? bias[gcol] : 0.f;
      #pragma unroll
      for (int reg = 0; reg < 4; ++reg) {
        float v = acc[im][in][reg] + bv;
        if (relu) v = fmaxf(v, 0.f);
        size_t idx = (size_t)(grow0 + reg) * HID + gcol;
        if (Cf) Cf[idx] = v;
        if (Cb) Cb[idx] = (bf16)v;
      }
    }
  }
}

// ---------------------------------------------------------------- flash semi-loss v7
// Same verified math/staging as sem5 (R6, 990us @ 23% MfmaUtil), re-tiled for
// 2 waves/SIMD: 512 thr (8 waves), wave owns 64 cols (bfrag 4x8 = 128 VGPR),
// LDS dbuf 2 x 64 KiB (128-row chunks), colsum-only in registers, one barrier
// per chunk, atomics only at kernel end.
//   z=0: X=P,Y=P -> Ra ; z=1: X=Q,Y=Q -> Rb ; z=2: X=P,Y=Q -> Cc ; z=3: X=Q,Y=P -> Cr
__global__ __launch_bounds__(512, 2) void flash_sem7(
    const bf16* __restrict__ P, const bf16* __restrict__ Q,
    float* __restrict__ Ra, float* __restrict__ Rb,
    float* __restrict__ Cr, float* __restrict__ Cc) {
  __shared__ bf16 As[2][128 * 256];      // 2 x 64 KiB
  int z = blockIdx.z;
  const bf16 *X, *Y;
  float* out;
  if (z == 0)      { X = P; Y = P; out = Ra; }
  else if (z == 1) { X = Q; Y = Q; out = Rb; }
  else if (z == 2) { X = P; Y = Q; out = Cc; }
  else             { X = Q; Y = P; out = Cr; }
  int tid = threadIdx.x, wid = tid >> 6, lane = tid & 63;
  int q = lane >> 4, li = lane & 15;
  int cw = blockIdx.x * 512 + wid * 64;   // this wave's column base
  // stationary Y fragments: 4 col-tiles x 8 k-steps (128 VGPR)
  bf16x8 bfrag[4][8];
  #pragma unroll
  for (int in = 0; in < 4; ++in) {
    const bf16* Yr = Y + (size_t)(cw + in * 16 + li) * HID + q * 8;
    #pragma unroll
    for (int kk = 0; kk < 8; ++kk)
      bfrag[in][kk] = *(const bf16x8*)(Yr + kk * 32);
  }
  float cs[4] = {};
  int i0 = blockIdx.y * 8192;
  int l5 = lane >> 5, cp = lane & 31;
  auto stage = [&](int chunk, int b) {
    const bf16* src = X + (size_t)(i0 + chunk * 128) * HID;
    #pragma unroll
    for (int n = 0; n < 8; ++n) {
      int rl = wid * 16 + n * 2;              // wave-uniform LDS row pair
      int r = rl + l5;                        // row this lane feeds
      int csrc = cp ^ (r & 31);               // swizzled source 16B-chunk
      GLOAD_LDS16(src + (size_t)r * HID + csrc * 8, &As[b][rl * 256]);
    }
  };
  stage(0, 0);
  __syncthreads();
  for (int c = 0; c < 64; ++c) {
    int b = c & 1;
    if (c + 1 < 64) stage(c + 1, b ^ 1);
    const bf16* buf = &As[b][0];
    #pragma unroll
    for (int ii = 0; ii < 8; ++ii) {
      bf16x8 af[8];
      #pragma unroll
      for (int kk = 0; kk < 8; ++kk) {
        int row = ii * 16 + li;
        af[kk] = *(const bf16x8*)(buf + row * 256 + ((((kk * 4 + q) ^ (row & 31))) << 3));
      }
      f32x4 acc[4] = {};
      #pragma unroll
      for (int kk = 0; kk < 8; ++kk)
        #pragma unroll
        for (int in = 0; in < 4; ++in)
          acc[in] = __builtin_amdgcn_mfma_f32_16x16x32_bf16(af[kk], bfrag[in][kk], acc[in], 0, 0, 0);
      #pragma unroll
      for (int in = 0; in < 4; ++in)
        #pragma unroll
        for (int reg = 0; reg < 4; ++reg)
          cs[in] += exp2f(acc[in][reg] * LOG2E_2);
    }
    __syncthreads();   // drains prefetch vmcnt + protects dbuf swap
  }
  #pragma unroll
  for (int in = 0; in < 4; ++in) {
    float v = cs[in];
    v += __shfl_xor(v, 16);
    v += __shfl_xor(v, 32);
    if (q == 0) atomicAdd(&out[cw + in * 16 + li], v);   // 2 row-half blocks contend
  }
}

// ---------------------------------------------------------------- l2norm (batched, one wave/row)
struct NormB { const float* X[3]; float* outF[3]; bf16* outB[3]; };
__global__ void l2norm_b(NormB n) {
  int j = blockIdx.y;
  int wid = threadIdx.x >> 6, lane = threadIdx.x & 63;
  int r = blockIdx.x * 4 + wid;
  float4 a = ((const float4*)(n.X[j] + (size_t)r * HID))[lane];
  float s = a.x * a.x + a.y * a.y + a.z * a.z + a.w * a.w;
  #pragma unroll
  for (int off = 1; off < 64; off <<= 1) s += __shfl_xor(s, off);
  float inv = 1.0f / fmaxf(sqrtf(s), 1e-12f);
  a.x *= inv; a.y *= inv; a.z *= inv; a.w *= inv;
  if (n.outF[j]) ((float4*)(n.outF[j] + (size_t)r * HID))[lane] = a;
  if (n.outB[j]) {
    bf16x4 b = {(bf16)a.x, (bf16)a.y, (bf16)a.z, (bf16)a.w};
    *(bf16x4*)(n.outB[j] + (size_t)r * HID + lane * 4) = b;
  }
}

// ---------------------------------------------------------------- tail: contrastive (y=0) + sem finalize (y=1)
__global__ void tail_k(const float* __restrict__ proj, const float* __restrict__ vn,
                       const float* __restrict__ ue, const int* __restrict__ nbr,
                       const int* __restrict__ neg,
                       const float* __restrict__ P, const float* __restrict__ Q2,
                       const float* __restrict__ Ra, const float* __restrict__ Rb,
                       const float* __restrict__ Cr, const float* __restrict__ Cc,
                       float* __restrict__ sums) {
  int wid = threadIdx.x >> 6, lane = threadIdx.x & 63;
  int n = blockIdx.x * 4 + wid;
  if (blockIdx.y == 0) {
    float4 p = ((const float4*)(proj + (size_t)n * HID))[lane];
    float4 v = ((const float4*)(vn + (size_t)n * HID))[lane];
    float du[SAMP], dn[SAMP];
    for (int s = 0; s < SAMP; ++s) {
      int iu = nbr[n * SAMP + s];
      float4 u = ((const float4*)(ue + (size_t)iu * HID))[lane];
      float d = p.x * u.x + p.y * u.y + p.z * u.z + p.w * u.w;
      #pragma unroll
      for (int off = 1; off < 64; off <<= 1) d += __shfl_xor(d, off);
      du[s] = d;
      int iv = neg[n * SAMP + s];
      float4 w = ((const float4*)(vn + (size_t)iv * HID))[lane];
      float d2 = v.x * w.x + v.y * w.y + v.z * w.z + v.w * w.w;
      #pragma unroll
      for (int off = 1; off < 64; off <<= 1) d2 += __shfl_xor(d2, off);
      dn[s] = d2;
    }
    float negsum = 0.f;
    for (int s = 0; s < SAMP; ++s) negsum += expf(2.f * dn[s]);
    float ns = 0.f, ps = 0.f;
    for (int s = 0; s < SAMP; ++s) {
      float pl = 2.f * du[s];
      ns += logf(expf(pl) + negsum);
      ps += pl;
    }
    if (lane == 0) atomicAdd(&sums[0], ns - ps);   // LAMBDA = 1
  } else {
    float4 a = ((const float4*)(P + (size_t)n * HID))[lane];
    float4 b = ((const float4*)(Q2 + (size_t)n * HID))[lane];
    float d = a.x * b.x + a.y * b.y + a.z * b.z + a.w * b.w;
    #pragma unroll
    for (int off = 1; off < 64; off <<= 1) d += __shfl_xor(d, off);
    float db = expf(2.f * d);
    float e2 = expf(2.f);      // diag(refl) of unit-norm rows
    float l1 = -logf(db / (Ra[n] + Cr[n] - e2));
    float l2 = -logf(db / (Rb[n] + Cc[n] - e2));
    if (lane == 0) atomicAdd(&sums[1], 0.5f * (l1 + l2));
  }
}

__global__ void final_k(const float* __restrict__ sums, float* __restrict__ out) {
  float gacl = sums[0] / (float)(NN * SAMP);
  float sem = sums[1] / (float)NN;
  out[0] = gacl + 0.6f * sem;
  out[1] = gacl;
  out[2] = sem;
}

// ---------------------------------------------------------------- launch
extern "C" void kernel_launch(void* const* d_in, const int* in_sizes, int n_in,
                              void* d_out, int out_size, void* d_ws, size_t ws_size,
                              hipStream_t stream) {
  (void)in_sizes; (void)n_in; (void)out_size; (void)ws_size;
  const float* adj1 = (const float*)d_in[0];
  const float* adj2 = (const float*)d_in[1];
  const float* x1 = (const float*)d_in[2];
  const float* x2 = (const float*)d_in[3];
  const int* nbr = (const int*)d_in[4];
  const int* neg = (const int*)d_in[5];
  const float* W1 = (const float*)d_in[6];
  const float* b1 = (const float*)d_in[7];
  const float* W2 = (const float*)d_in[8];
  const float* b2 = (const float*)d_in[9];
  const float* tW1 = (const float*)d_in[10];
  const float* tb1 = (const float*)d_in[11];
  const float* tW2 = (const float*)d_in[12];
  const float* tb2 = (const float*)d_in[13];
  const float* pB[3] = {(const float*)d_in[15], (const float*)d_in[17], (const float*)d_in[19]};
  const float* sB[3] = {(const float*)d_in[21], (const float*)d_in[23], (const float*)d_in[25]};

  char* w = (char*)d_ws;
  auto alloc = [&](size_t bytes) -> char* {
    char* p = w;
    w += (bytes + 255) & ~(size_t)255;
    return p;
  };
  // accumulators first (one memset covers them)
  float* Ra = (float*)alloc((size_t)NN * 4);
  float* Rb = (float*)alloc((size_t)NN * 4);
  float* Cr = (float*)alloc((size_t)NN * 4);
  float* Cc = (float*)alloc((size_t)NN * 4);
  float* sums = (float*)alloc(256);             // [0]=gacl_sum, [1]=sem_sum
  size_t accBytes = (size_t)(w - (char*)d_ws);

  int* c1cols = (int*)alloc((size_t)NN * CAP * 4);
  int* c1cnt = (int*)alloc((size_t)NN * 4);
  int* c2cols = (int*)alloc((size_t)NN * CAP * 4);
  int* c2cnt = (int*)alloc((size_t)NN * 4);
  bf16* x1b = (bf16*)alloc((size_t)NN * IND * 2);
  bf16* x2b = (bf16*)alloc((size_t)NN * IND * 2);
  bf16* W1t = (bf16*)alloc((size_t)IND * HID * 2);
  bf16* tW1t = (bf16*)alloc((size_t)IND * HID * 2);
  bf16* W2t = (bf16*)alloc((size_t)HID * HID * 2);
  bf16* tW2t = (bf16*)alloc((size_t)HID * HID * 2);
  bf16* pWt[3], *sWt[3];
  for (int i = 0; i < 3; ++i) pWt[i] = (bf16*)alloc((size_t)HID * HID * 2);
  for (int i = 0; i < 3; ++i) sWt[i] = (bf16*)alloc((size_t)HID * HID * 2);
  const size_t BB = (size_t)NN * HID * 2;       // 8 MiB bf16 buffers
  bf16* xw1b = (bf16*)alloc(BB);
  bf16* xw2b = (bf16*)alloc(BB);
  bf16* xt1b = (bf16*)alloc(BB);
  bf16* gwb = (bf16*)alloc(BB);
  bf16* utwb = (bf16*)alloc(BB);
  bf16* h1b = (bf16*)alloc(BB);
  bf16* h2b = (bf16*)alloc(BB);
  bf16* gb_ = (bf16*)alloc(BB);
  bf16* h3b = (bf16*)alloc(BB);
  bf16* utb = (bf16*)alloc(BB);
  bf16* mA = (bf16*)alloc(BB);
  bf16* mB = (bf16*)alloc(BB);
  bf16* mB1 = (bf16*)alloc(BB);
  bf16* mB2 = (bf16*)alloc(BB);
  bf16* Pb = (bf16*)alloc(BB);
  bf16* Qb = (bf16*)alloc(BB);
  const size_t FB = (size_t)NN * HID * 4;       // 16 MiB f32 buffers
  float* u_emd = (float*)alloc(FB);
  float* v_norm = (float*)alloc(FB);
  float* projected = (float*)alloc(FB);
  float* h1p = (float*)alloc(FB);
  float* h2p = (float*)alloc(FB);
  float* mlp_out = (float*)alloc(FB);
  float* s3a = (float*)alloc(FB);
  float* s3b = (float*)alloc(FB);

  hipMemsetAsync(d_ws, 0, accBytes, stream);

  WtArgs wa;
  const float* wsrc[10] = {W1, tW1, W2, tW2,
                           (const float*)d_in[14], (const float*)d_in[16], (const float*)d_in[18],
                           (const float*)d_in[20], (const float*)d_in[22], (const float*)d_in[24]};
  bf16* wdst[10] = {W1t, tW1t, W2t, tW2t, pWt[0], pWt[1], pWt[2], sWt[0], sWt[1], sWt[2]};
  int wk[10] = {IND, IND, HID, HID, HID, HID, HID, HID, HID, HID};
  for (int i = 0; i < 10; ++i) { wa.src[i] = wsrc[i]; wa.dst[i] = wdst[i]; wa.K[i] = wk[i]; }
  cvt_weights<<<dim3(512, 10), 256, 0, stream>>>(wa);
  cvt_x<<<dim3(2048, 2), 256, 0, stream>>>(x1, x1b, x2, x2b);
  scan_adj<<<dim3(NN, 2), 256, 0, stream>>>(adj1, adj2, c1cols, c1cnt, c2cols, c2cnt);

  // xw1 = x1@W1, xw2 = x2@W1, xt1 = x1@tW1  (K=512, batched, bf16 out)
  {
    GemmB g = {};
    g.A[0] = x1b; g.Bt[0] = W1t; g.Cb[0] = xw1b;
    g.A[1] = x2b; g.Bt[1] = W1t; g.Cb[1] = xw2b;
    g.A[2] = x1b; g.Bt[2] = tW1t; g.Cb[2] = xt1b;
    gemm_b<<<dim3(128, 2, 3), 256, 0, stream>>>(g, IND, 0);
  }
  // h1 = A1@xw1+b1, h2 = A1@xw2+b1, g = A2@xw1+b1, ut = A2@xt1+tb1
  {
    SpmmB s = {};
    s.cols[0] = c1cols; s.cnt[0] = c1cnt; s.X[0] = xw1b; s.bias[0] = b1; s.outB[0] = h1b;
    s.cols[1] = c1cols; s.cnt[1] = c1cnt; s.X[1] = xw2b; s.bias[1] = b1; s.outB[1] = h2b;
    s.cols[2] = c2cols; s.cnt[2] = c2cnt; s.X[2] = xw1b; s.bias[2] = b1; s.outB[2] = gb_;
    s.cols[3] = c2cols; s.cnt[3] = c2cnt; s.X[3] = xt1b; s.bias[3] = tb1; s.outB[3] = utb;
    spmm_b<<<dim3(NN / 4, 4), 256, 0, stream>>>(s);
  }
  // gw = g@W2, utw = ut@tW2 (K=256, batched, bf16 out)
  {
    GemmB g = {};
    g.A[0] = gb_; g.Bt[0] = W2t; g.Cb[0] = gwb;
    g.A[1] = utb; g.Bt[1] = tW2t; g.Cb[1] = utwb;
    gemm_b<<<dim3(128, 2, 2), 256, 0, stream>>>(g, HID, 0);
  }
  // h3 = A2@gw+b2 (-> d_out+3, h3b, v_norm) ; u_emd = l2norm(A2@utw+tb2)
  float* h3out = ((float*)d_out) + 3;
  {
    SpmmB s = {};
    s.cols[0] = c2cols; s.cnt[0] = c2cnt; s.X[0] = gwb; s.bias[0] = b2;
    s.outF[0] = h3out; s.outB[0] = h3b; s.outNF[0] = v_norm;
    s.cols[1] = c2cols; s.cnt[1] = c2cnt; s.X[1] = utwb; s.bias[1] = tb2;
    s.outNF[1] = u_emd;
    spmm_b<<<dim3(NN / 4, 2), 256, 0, stream>>>(s);
  }
  // MLP layer 1 (relu): proj(h3b), sem(h1b), sem(h2b)
  {
    GemmB g = {};
    g.A[0] = h3b; g.Bt[0] = pWt[0]; g.bias[0] = pB[0]; g.Cb[0] = mA;
    g.A[1] = h1b; g.Bt[1] = sWt[0]; g.bias[1] = sB[0]; g.Cb[1] = gb_;
    g.A[2] = h2b; g.Bt[2] = sWt[0]; g.bias[2] = sB[0]; g.Cb[2] = utb;
    gemm_b<<<dim3(128, 2, 3), 256, 0, stream>>>(g, HID, 1);
  }
  // MLP layer 2 (relu)
  {
    GemmB g = {};
    g.A[0] = mA; g.Bt[0] = pWt[1]; g.bias[0] = pB[1]; g.Cb[0] = mB;
    g.A[1] = gb_; g.Bt[1] = sWt[1]; g.bias[1] = sB[1]; g.Cb[1] = mB1;
    g.A[2] = utb; g.Bt[2] = sWt[1]; g.bias[2] = sB[1]; g.Cb[2] = mB2;
    gemm_b<<<dim3(128, 2, 3), 256, 0, stream>>>(g, HID, 1);
  }
  // MLP layer 3 (no relu) -> f32
  {
    GemmB g = {};
    g.A[0] = mB; g.Bt[0] = pWt[2]; g.bias[0] = pB[2]; g.Cf[0] = mlp_out;
    g.A[1] = mB1; g.Bt[1] = sWt[2]; g.bias[1] = sB[2]; g.Cf[1] = s3a;
    g.A[2] = mB2; g.Bt[2] = sWt[2]; g.bias[2] = sB[2]; g.Cf[2] = s3b;
    gemm_b<<<dim3(128, 2, 3), 256, 0, stream>>>(g, HID, 0);
  }
  // l2norm: projected, h1p(+Pb), h2p(+Qb)
  {
    NormB nb2 = {};
    nb2.X[0] = mlp_out; nb2.outF[0] = projected;
    nb2.X[1] = s3a; nb2.outF[1] = h1p; nb2.outB[1] = Pb;
    nb2.X[2] = s3b; nb2.outF[2] = h2p; nb2.outB[2] = Qb;
    l2norm_b<<<dim3(NN / 4, 3), 256, 0, stream>>>(nb2);
  }

  flash_sem7<<<dim3(32, 2, 4), 512, 0, stream>>>(Pb, Qb, Ra, Rb, Cr, Cc);
  tail_k<<<dim3(NN / 4, 2), 256, 0, stream>>>(projected, v_norm, u_emd, nbr, neg,
                                              h1p, h2p, Ra, Rb, Cr, Cc, sums);
  final_k<<<1, 1, 0, stream>>>(sums, (float*)d_out);
}